// Round 11
// baseline (771.562 us; speedup 1.0000x reference)
//
#include <hip/hip_runtime.h>

#define T_TOK 2048
#define HID   2048
#define INTER 768
#define NE    32
#define NSLOT 8192   // T_TOK * TOP_K
#define MAXT  96     // max (expert, mt) tiles at BM=128

typedef short bf16x8 __attribute__((ext_vector_type(8)));
typedef float f32x4  __attribute__((ext_vector_type(4)));

__device__ __forceinline__ unsigned short f2b(float f){
  unsigned u = __builtin_bit_cast(unsigned, f);
  u += 0x7fffu + ((u >> 16) & 1u);      // RNE
  return (unsigned short)(u >> 16);
}
__device__ __forceinline__ unsigned pk2(float a, float b){
  return (unsigned)f2b(a) | ((unsigned)f2b(b) << 16);
}
__device__ __forceinline__ float b2f(unsigned short u){
  unsigned x = ((unsigned)u) << 16;
  return __builtin_bit_cast(float, x);
}

// Non-draining workgroup barrier (r10-proven): __syncthreads would emit
// s_waitcnt vmcnt(0) and drain the 2-deep global prefetch.
__device__ __forceinline__ void wgbar(){
  asm volatile("s_waitcnt lgkmcnt(0)" ::: "memory");
  __builtin_amdgcn_s_barrier();
  __builtin_amdgcn_sched_barrier(0);
}

// ---------------- workspace layout (bytes) ----------------
#define XB_OFF    0ul           // bf16 x  [2048][2048]  = 8388608
#define GBUF_OFF  8388608ul     // bf16 g -> h in place [8192][768] = 12582912
#define TKW_OFF   20971520ul
#define TKI_OFF   21004288ul
#define ROWS_OFF  21037056ul
#define WTS_OFF   21069824ul
#define OFFS_OFF  21102592ul
#define LOGIT_OFF 21102848ul    // zeroed
#define CNT_OFF   21364992ul    // zeroed
#define FILL_OFF  21365120ul    // zeroed
#define TLIST_OFF 21365248ul
#define T2S_OFF   21365760ul    // i32 tok2slot [8192] = 32768
#define UBUF_OFF  21398528ul    // bf16 u [8192][768] = 12582912
#define SBUF_OFF  33981440ul    // bf16 per-slot down out [8192][2048] = 33554432
#define WS_NEED   (SBUF_OFF + 33554432ul)   // ~67.5 MB
#define ZERO_OFF  21102848ul
#define ZERO_SZ   (262144ul + 128ul + 128ul)

// ---------------- x fp32 -> bf16 ----------------
__global__ void convert_x_kernel(const float* __restrict__ x, ushort* __restrict__ xb){
  int i = (blockIdx.x * 256 + threadIdx.x) * 8;
  float4 a = *(const float4*)(x + i);
  float4 b = *(const float4*)(x + i + 4);
  uint4 o;
  o.x = pk2(a.x, a.y);
  o.y = pk2(a.z, a.w);
  o.z = pk2(b.x, b.y);
  o.w = pk2(b.z, b.w);
  *(uint4*)(xb + i) = o;
}

// ---------------- router logits (fp32 GEMM, split-K atomic) ----------------
__global__ void router_gemm(const float* __restrict__ x, const float* __restrict__ wr,
                            float* __restrict__ logits){
  const int tt = blockIdx.x;
  const int kb = blockIdx.y;
  __shared__ float xs[64 * 64];
  __shared__ float wsm[64 * 32];
  const int tid = threadIdx.x;
  const int r = tid >> 5, e = tid & 31;
  float acc[8];
#pragma unroll
  for (int i = 0; i < 8; i++) acc[i] = 0.0f;

  for (int sub = 0; sub < 4; ++sub){
    const int k0 = kb * 256 + sub * 64;
    __syncthreads();
#pragma unroll
    for (int j = 0; j < 4; j++){
      int f4 = tid + j * 256;
      int row = f4 >> 4, c4 = f4 & 15;
      float4 v = *(const float4*)(x + (size_t)(tt * 64 + row) * HID + k0 + c4 * 4);
      *(float4*)(xs + row * 64 + c4 * 4) = v;
    }
#pragma unroll
    for (int j = 0; j < 2; j++){
      int f4 = tid + j * 256;
      int row = f4 >> 3, c4 = f4 & 7;
      float4 v = *(const float4*)(wr + (size_t)(k0 + row) * NE + c4 * 4);
      *(float4*)(wsm + row * NE + c4 * 4) = v;
    }
    __syncthreads();
    for (int kk = 0; kk < 64; kk++){
      float wv = wsm[kk * NE + e];
#pragma unroll
      for (int i = 0; i < 8; i++) acc[i] += xs[(r + i * 8) * 64 + kk] * wv;
    }
  }
#pragma unroll
  for (int i = 0; i < 8; i++)
    atomicAdd(&logits[(size_t)(tt * 64 + r + i * 8) * NE + e], acc[i]);
}

// ---------------- softmax + top-4 + renorm + counts ----------------
__global__ void topk_kernel(const float* __restrict__ logits, float* __restrict__ topk_w,
                            int* __restrict__ topk_i, int* __restrict__ counts){
  int t = blockIdx.x * blockDim.x + threadIdx.x;
  if (t >= T_TOK) return;
  float l[32];
  const float4* lp = (const float4*)(logits + (size_t)t * NE);
#pragma unroll
  for (int i = 0; i < 8; i++){
    float4 v = lp[i];
    l[i*4+0] = v.x; l[i*4+1] = v.y; l[i*4+2] = v.z; l[i*4+3] = v.w;
  }
  float m = l[0];
#pragma unroll
  for (int i = 1; i < 32; i++) m = fmaxf(m, l[i]);
#pragma unroll
  for (int i = 0; i < 32; i++) l[i] = __expf(l[i] - m);
  float wsel[4]; int isel[4];
#pragma unroll
  for (int k = 0; k < 4; k++){
    float best = l[0]; int bi = 0;
#pragma unroll
    for (int i = 1; i < 32; i++){ if (l[i] > best){ best = l[i]; bi = i; } }
    wsel[k] = best; isel[k] = bi; l[bi] = -1.0f;
  }
  float s4 = wsel[0] + wsel[1] + wsel[2] + wsel[3];
  float inv = 1.0f / s4;
#pragma unroll
  for (int k = 0; k < 4; k++){
    topk_w[t * 4 + k] = wsel[k] * inv;
    topk_i[t * 4 + k] = isel[k];
    atomicAdd(&counts[isel[k]], 1);
  }
}

__global__ void prefix_kernel(const int* __restrict__ counts, int* __restrict__ offsets,
                              int* __restrict__ tlist){
  if (threadIdx.x == 0){
    int a = 0; offsets[0] = 0; int nt_ = 0;
    for (int e = 0; e < NE; e++){
      int c = counts[e];
      for (int m = 0; m * 128 < c && nt_ < MAXT; m++) tlist[nt_++] = e | (m << 16);
      a += c; offsets[e + 1] = a;
    }
    for (; nt_ < MAXT; nt_++) tlist[nt_] = -1;
  }
}

__global__ void scatter_kernel(const int* __restrict__ topk_i, const float* __restrict__ topk_w,
                               const int* __restrict__ offsets, int* __restrict__ fill,
                               int* __restrict__ rows, float* __restrict__ wts,
                               int* __restrict__ t2s){
  int gid = blockIdx.x * 256 + threadIdx.x;
  int t = gid >> 2;
  int e = topk_i[gid];
  int pos = atomicAdd(&fill[e], 1);
  int s = offsets[e] + pos;
  rows[s] = t;
  wts[s] = topk_w[gid];
  t2s[gid] = s;
}

// ---------------- gate/up GEMM (split matrices) ----------------
// BM=128, BN=128, BK=32, 512 thr (8 waves = 4m x 2n, 8 MFMA/tile/wave).
// LDS 40 KB (2 x (A 5120 + B 5120) ush) -> 3 blocks/CU; (512,6) caps total
// regs (~45 VGPR + 32 AGPR <= 85) for 24 waves/CU. Coalesced float4 B loads
// (512B segments). 2-deep reg-set pipeline + wgbar (r10 schedule). Bank
// conflicts deliberately ignored (r10 analysis: 1.4e7 cyc = 0.02% of time).
#define NTK_GU 64
#define GA_SZ 5120            // A: 128 rows * 40 ush
#define GBUF_USH 10240        // + B: 128 cols * 40 ush
__global__ __launch_bounds__(512, 6) void guv_kernel(
    const ushort* __restrict__ xb, const float* __restrict__ wg,
    const float* __restrict__ wu, const int* __restrict__ rows,
    const int* __restrict__ counts, const int* __restrict__ offsets,
    const int* __restrict__ tlist, ushort* __restrict__ gbuf,
    ushort* __restrict__ ubuf)
{
  const int w = tlist[blockIdx.y];
  if (w < 0) return;
  const int e = w & 0xffff, mt = w >> 16;
  const int mat = blockIdx.x & 1, nt = blockIdx.x >> 1;   // nt 0..5
  const int cnt = counts[e], off = offsets[e];
  const int n0 = nt * 128;

  __shared__ __align__(16) ushort lds[2 * GBUF_USH];  // 40960 B

  const int tid = threadIdx.x;
  const int lane = tid & 63, wv = tid >> 6;

  // A staging: row ar, 16B chunk aq
  const int ar = tid >> 2, aq = tid & 3;
  const int srow = mt * 128 + ar;
  const int tokA = rows[off + (srow < cnt ? srow : 0)];
  const ushort* agp = xb + (size_t)tokA * HID + aq * 8;
  const int adst = ar * 40 + aq * 8;

  // B staging: thread -> k-rows {2q, 2q+1}, cols cq*4..cq*4+3 (float4)
  const int q = tid >> 5, cq = tid & 31;
  const float* wsel = mat ? wu : wg;
  const float* bgp = wsel + (size_t)e * (HID * INTER) + (size_t)(2 * q) * INTER + n0 + cq * 4;
  // write: 4x b32 (k-pair packed) at col c = cq*4+i, dw offset q

  // compute roles: 4m x 2n
  const int wm = wv >> 1, wn = wv & 1;
  const int fr = lane & 15, ko = lane >> 4;
  int aoff[2], boff[4];
#pragma unroll
  for (int mf = 0; mf < 2; mf++) aoff[mf] = (wm * 32 + mf * 16 + fr) * 40 + ko * 8;
#pragma unroll
  for (int nf = 0; nf < 4; nf++) boff[nf] = GA_SZ + (wn * 64 + nf * 16 + fr) * 40 + ko * 8;

  f32x4 acc[2][4];
#pragma unroll
  for (int i = 0; i < 2; i++)
#pragma unroll
    for (int j = 0; j < 4; j++) acc[i][j] = (f32x4)(0.0f);

  uint4 a0, a1;
  float4 b0r0, b0r1, b1r0, b1r1;

  auto loadSet = [&](int k0, uint4 &aa, float4 &r0, float4 &r1){
    aa = *(const uint4*)(agp + k0);
    r0 = *(const float4*)(bgp + (size_t)k0 * INTER);
    r1 = *(const float4*)(bgp + (size_t)k0 * INTER + INTER);
  };
  auto writeSet = [&](int base, const uint4 &aa, const float4 &r0, const float4 &r1){
    *(uint4*)(lds + base + adst) = aa;
    uint* bd = (uint*)(lds + base + GA_SZ);
#pragma unroll
    for (int i = 0; i < 4; i++){
      int c = cq * 4 + i;
      bd[c * 20 + q] = pk2(((const float*)&r0)[i], ((const float*)&r1)[i]);
    }
  };
  auto compute = [&](int base){
    bf16x8 a[2], b[4];
#pragma unroll
    for (int mf = 0; mf < 2; mf++) a[mf] = *(const bf16x8*)(lds + base + aoff[mf]);
#pragma unroll
    for (int nf = 0; nf < 4; nf++) b[nf] = *(const bf16x8*)(lds + base + boff[nf]);
#pragma unroll
    for (int mf = 0; mf < 2; mf++)
#pragma unroll
      for (int nf = 0; nf < 4; nf++)
        acc[mf][nf] = __builtin_amdgcn_mfma_f32_16x16x32_bf16(a[mf], b[nf], acc[mf][nf], 0, 0, 0);
  };

  loadSet(0,  a0, b0r0, b0r1);
  loadSet(32, a1, b1r0, b1r1);
  writeSet(0, a0, b0r0, b0r1);
  wgbar();

  for (int t = 0; t < NTK_GU; t += 2){
    if (t + 2 < NTK_GU) loadSet((t + 2) * 32, a0, b0r0, b0r1);
    compute(0);
    writeSet(GBUF_USH, a1, b1r0, b1r1);
    wgbar();
    if (t + 3 < NTK_GU) loadSet((t + 3) * 32, a1, b1r0, b1r1);
    compute(GBUF_USH);
    if (t + 2 < NTK_GU){ writeSet(0, a0, b0r0, b0r1); wgbar(); }
  }

  // epilogue: 4 nf x 16 lanes = 128 B bf16 per wave-row (full lines)
  ushort* obuf = mat ? ubuf : gbuf;
#pragma unroll
  for (int mf = 0; mf < 2; mf++)
#pragma unroll
    for (int j = 0; j < 4; j++){
      int rl = wm * 32 + mf * 16 + ko * 4 + j;
      int gr = mt * 128 + rl;
      if (gr < cnt){
        size_t rb = (size_t)(off + gr) * INTER + n0;
#pragma unroll
        for (int nf = 0; nf < 4; nf++)
          obuf[rb + wn * 64 + nf * 16 + fr] = f2b(acc[mf][nf][j]);
      }
    }
}

// ---------------- fuse: h = silu(g) * u * wt (in place over gbuf) ----------------
__global__ void fuse_kernel(ushort* __restrict__ gbuf, const ushort* __restrict__ ubuf,
                            const float* __restrict__ wts){
  const int s = blockIdx.x;
  const int c = threadIdx.x * 4;
  const float wt = wts[s];
  size_t base = (size_t)s * INTER + c;
  uint2 gv = *(const uint2*)(gbuf + base);
  uint2 uv = *(const uint2*)(ubuf + base);
  float h[4];
  {
    float g0 = b2f((unsigned short)gv.x),        u0 = b2f((unsigned short)uv.x);
    float g1 = b2f((unsigned short)(gv.x >> 16)), u1 = b2f((unsigned short)(uv.x >> 16));
    float g2 = b2f((unsigned short)gv.y),        u2 = b2f((unsigned short)uv.y);
    float g3 = b2f((unsigned short)(gv.y >> 16)), u3 = b2f((unsigned short)(uv.y >> 16));
    h[0] = (g0 / (1.0f + __expf(-g0))) * u0 * wt;
    h[1] = (g1 / (1.0f + __expf(-g1))) * u1 * wt;
    h[2] = (g2 / (1.0f + __expf(-g2))) * u2 * wt;
    h[3] = (g3 / (1.0f + __expf(-g3))) * u3 * wt;
  }
  uint2 o; o.x = pk2(h[0], h[1]); o.y = pk2(h[2], h[3]);
  *(uint2*)(gbuf + base) = o;
}

// ---------------- down GEMM: BM=128, BN=256, BK=32, 24 K-tiles ----------------
// 8 waves = 4m x 2n, acc[2][8] (64 AGPR). SLOT: per-slot bf16 rows (256B
// full lines, no atomics) + combine pass; else atomic fp32.
#define NTK_DN 24
#define DA_SZ 5120            // A: 128 * 40
#define DBUF_USH 15360        // + B: 256 * 40
template<bool SLOT>
__global__ __launch_bounds__(512, 4) void down_kernel(
    const ushort* __restrict__ hbuf, const float* __restrict__ wd,
    const int* __restrict__ rows, const int* __restrict__ counts,
    const int* __restrict__ offsets, const int* __restrict__ tlist,
    float* __restrict__ outp, ushort* __restrict__ sbuf)
{
  const int w = tlist[blockIdx.y];
  if (w < 0) return;
  const int e = w & 0xffff, mt = w >> 16;
  const int nt = blockIdx.x;   // 0..7
  const int cnt = counts[e], off = offsets[e];
  const int n0 = nt * 256;

  __shared__ __align__(16) ushort lds[2 * DBUF_USH];  // 61440 B

  const int tid = threadIdx.x;
  const int lane = tid & 63, wv = tid >> 6;

  const int ar = tid >> 2, aq = tid & 3;
  const int srow = mt * 128 + ar;
  const int slotA = off + (srow < cnt ? srow : 0);
  const ushort* agp = hbuf + (size_t)slotA * INTER + aq * 8;
  const int adst = ar * 40 + aq * 8;

  const int q = tid >> 5, cq = tid & 31;
  const float* bgp = wd + (size_t)e * (INTER * HID) + (size_t)(2 * q) * HID + n0 + cq * 4;

  const int wm = wv >> 1, wn = wv & 1;
  const int fr = lane & 15, ko = lane >> 4;
  int aoff[2], boff[8];
#pragma unroll
  for (int mf = 0; mf < 2; mf++) aoff[mf] = (wm * 32 + mf * 16 + fr) * 40 + ko * 8;
#pragma unroll
  for (int nf = 0; nf < 8; nf++) boff[nf] = DA_SZ + (wn * 128 + nf * 16 + fr) * 40 + ko * 8;

  f32x4 acc[2][8];
#pragma unroll
  for (int i = 0; i < 2; i++)
#pragma unroll
    for (int j = 0; j < 8; j++) acc[i][j] = (f32x4)(0.0f);

  uint4 a0, a1;
  float4 s0[4], s1[4];   // [r0c0, r1c0, r0c1, r1c1]

  auto loadSet = [&](int k0, uint4 &aa, float4 *bb){
    aa = *(const uint4*)(agp + k0);
    const float* p = bgp + (size_t)k0 * HID;
    bb[0] = *(const float4*)(p);
    bb[1] = *(const float4*)(p + HID);
    bb[2] = *(const float4*)(p + 128);
    bb[3] = *(const float4*)(p + HID + 128);
  };
  auto writeSet = [&](int base, const uint4 &aa, const float4 *bb){
    *(uint4*)(lds + base + adst) = aa;
    uint* bd = (uint*)(lds + base + DA_SZ);
#pragma unroll
    for (int i = 0; i < 4; i++){
      int c = cq * 4 + i;
      bd[c * 20 + q]         = pk2(((const float*)&bb[0])[i], ((const float*)&bb[1])[i]);
      bd[(c + 128) * 20 + q] = pk2(((const float*)&bb[2])[i], ((const float*)&bb[3])[i]);
    }
  };
  auto compute = [&](int base){
    bf16x8 a[2], b[8];
#pragma unroll
    for (int mf = 0; mf < 2; mf++) a[mf] = *(const bf16x8*)(lds + base + aoff[mf]);
#pragma unroll
    for (int nf = 0; nf < 8; nf++) b[nf] = *(const bf16x8*)(lds + base + boff[nf]);
#pragma unroll
    for (int mf = 0; mf < 2; mf++)
#pragma unroll
      for (int nf = 0; nf < 8; nf++)
        acc[mf][nf] = __builtin_amdgcn_mfma_f32_16x16x32_bf16(a[mf], b[nf], acc[mf][nf], 0, 0, 0);
  };

  loadSet(0,  a0, s0);
  loadSet(32, a1, s1);
  writeSet(0, a0, s0);
  wgbar();

  for (int t = 0; t < NTK_DN; t += 2){
    if (t + 2 < NTK_DN) loadSet((t + 2) * 32, a0, s0);
    compute(0);
    writeSet(DBUF_USH, a1, s1);
    wgbar();
    if (t + 3 < NTK_DN) loadSet((t + 3) * 32, a1, s1);
    compute(DBUF_USH);
    if (t + 2 < NTK_DN){ writeSet(0, a0, s0); wgbar(); }
  }

#pragma unroll
  for (int mf = 0; mf < 2; mf++)
#pragma unroll
    for (int j = 0; j < 4; j++){
      int rl = wm * 32 + mf * 16 + ko * 4 + j;
      int gr = mt * 128 + rl;
      if (gr < cnt){
        if (SLOT){
          ushort* obase = sbuf + (size_t)(off + gr) * HID + n0;
#pragma unroll
          for (int nf = 0; nf < 8; nf++)
            obase[wn * 128 + nf * 16 + fr] = f2b(acc[mf][nf][j]);
        } else {
          int tok = rows[off + gr];
          float* obase = outp + (size_t)tok * HID + n0;
#pragma unroll
          for (int nf = 0; nf < 8; nf++)
            atomicAdd(obase + wn * 128 + nf * 16 + fr, acc[mf][nf][j]);
        }
      }
    }
}

// ---------------- combine: out[t] = sum of token t's 4 bf16 slot rows ----------------
__global__ void combine_kernel(const ushort* __restrict__ sbuf, const int* __restrict__ t2s,
                               float* __restrict__ out){
  const int t = blockIdx.x;
  const int c = threadIdx.x * 8;   // 256 thr x 8 = 2048
  const int s0 = t2s[t * 4 + 0], s1 = t2s[t * 4 + 1];
  const int s2 = t2s[t * 4 + 2], s3 = t2s[t * 4 + 3];
  uint4 a = *(const uint4*)(sbuf + (size_t)s0 * HID + c);
  uint4 b = *(const uint4*)(sbuf + (size_t)s1 * HID + c);
  uint4 d = *(const uint4*)(sbuf + (size_t)s2 * HID + c);
  uint4 g = *(const uint4*)(sbuf + (size_t)s3 * HID + c);
  float r[8];
#pragma unroll
  for (int i = 0; i < 4; i++){
    unsigned ua = ((const unsigned*)&a)[i], ub = ((const unsigned*)&b)[i];
    unsigned ud = ((const unsigned*)&d)[i], ug = ((const unsigned*)&g)[i];
    r[2*i]   = b2f((unsigned short)ua) + b2f((unsigned short)ub) +
               b2f((unsigned short)ud) + b2f((unsigned short)ug);
    r[2*i+1] = b2f((unsigned short)(ua >> 16)) + b2f((unsigned short)(ub >> 16)) +
               b2f((unsigned short)(ud >> 16)) + b2f((unsigned short)(ug >> 16));
  }
  float4 o0 = { r[0], r[1], r[2], r[3] };
  float4 o1 = { r[4], r[5], r[6], r[7] };
  *(float4*)(out + (size_t)t * HID + c)     = o0;
  *(float4*)(out + (size_t)t * HID + c + 4) = o1;
}

// ---------------- launch ----------------
extern "C" void kernel_launch(void* const* d_in, const int* in_sizes, int n_in,
                              void* d_out, int out_size, void* d_ws, size_t ws_size,
                              hipStream_t stream){
  const float* x  = (const float*)d_in[0];
  const float* wr = (const float*)d_in[1];
  const float* wg = (const float*)d_in[2];
  const float* wu = (const float*)d_in[3];
  const float* wd = (const float*)d_in[4];
  float* out = (float*)d_out;
  char* ws = (char*)d_ws;

  ushort* xb     = (ushort*)(ws + XB_OFF);
  ushort* gbuf   = (ushort*)(ws + GBUF_OFF);
  ushort* ubuf   = (ushort*)(ws + UBUF_OFF);
  ushort* sbuf   = (ushort*)(ws + SBUF_OFF);
  float*  topkw  = (float*)(ws + TKW_OFF);
  int*    topki  = (int*)(ws + TKI_OFF);
  int*    rows   = (int*)(ws + ROWS_OFF);
  float*  wts    = (float*)(ws + WTS_OFF);
  int*    offs   = (int*)(ws + OFFS_OFF);
  float*  logits = (float*)(ws + LOGIT_OFF);
  int*    counts = (int*)(ws + CNT_OFF);
  int*    fill   = (int*)(ws + FILL_OFF);
  int*    tlist  = (int*)(ws + TLIST_OFF);
  int*    t2s    = (int*)(ws + T2S_OFF);

  const bool slotpath = (ws_size >= WS_NEED);

  hipMemsetAsync(ws + ZERO_OFF, 0, ZERO_SZ, stream);

  convert_x_kernel<<<2048, 256, 0, stream>>>(x, xb);
  router_gemm<<<dim3(32, 8), 256, 0, stream>>>(x, wr, logits);
  topk_kernel<<<8, 256, 0, stream>>>(logits, topkw, topki, counts);
  prefix_kernel<<<1, 64, 0, stream>>>(counts, offs, tlist);
  scatter_kernel<<<32, 256, 0, stream>>>(topki, topkw, offs, fill, rows, wts, t2s);
  guv_kernel<<<dim3(12, MAXT), 512, 0, stream>>>(xb, wg, wu, rows, counts, offs, tlist, gbuf, ubuf);
  fuse_kernel<<<NSLOT, 192, 0, stream>>>(gbuf, ubuf, wts);
  if (slotpath){
    down_kernel<true><<<dim3(8, MAXT), 512, 0, stream>>>(gbuf, wd, rows, counts, offs, tlist, out, sbuf);
    combine_kernel<<<T_TOK, 256, 0, stream>>>(sbuf, t2s, out);
  } else {
    hipMemsetAsync(d_out, 0, (size_t)out_size * sizeof(float), stream);
    down_kernel<false><<<dim3(8, MAXT), 512, 0, stream>>>(gbuf, wd, rows, counts, offs, tlist, out, sbuf);
  }
}